// Round 4
// baseline (755.209 us; speedup 1.0000x reference)
//
#include <hip/hip_runtime.h>
#include <hip/hip_cooperative_groups.h>

namespace cg = cooperative_groups;

#define T_ 2
#define N_ 4096
#define E_ 4096
#define D_ 128
#define CAP 64     // max stored nnz per row/col; Binomial(4096,0.002) mean 8.2 -> P(>64) ~ 0
#define GRID 512   // 2 blocks/CU x 256 CU -- guaranteed co-resident with 17.4KB LDS, VGPR<=256
#define NTHR 256

// ---------------------------------------------------------------------------
// build: one WAVE per H row. 16 lane-coalesced float4 loads -> 64-bit nnz mask
// -> wave prefix scan -> ordered adjNE append (deterministic). Edge side via
// atomic append on padded counters (one per 64B line), canonicalized by sort.
__device__ __forceinline__ void build_row_wave(int row, int lane,
        const float* __restrict__ H, float* __restrict__ dVis,
        int* __restrict__ cntNE, int* __restrict__ adjNE,
        int* __restrict__ cntENp, int* __restrict__ adjEN) {
    int t = row >> 12;
    const float4* row4 = (const float4*)(H + (size_t)row * E_);
    unsigned long long mask = 0;
    #pragma unroll
    for (int i = 0; i < 16; ++i) {
        float4 v = row4[i * 64 + lane];
        unsigned mm = 0;
        if (v.x != 0.0f) mm |= 1u;
        if (v.y != 0.0f) mm |= 2u;
        if (v.z != 0.0f) mm |= 4u;
        if (v.w != 0.0f) mm |= 8u;
        mask |= (unsigned long long)mm << (i * 4);
    }
    int cnt = __popcll(mask);
    int incl = cnt;
    #pragma unroll
    for (int off = 1; off < 64; off <<= 1) {
        int u = __shfl_up(incl, off);
        if (lane >= off) incl += u;
    }
    int pos = incl - cnt;
    int* adjrow = adjNE + (size_t)row * CAP;
    int n_id = row & (N_ - 1);
    unsigned long long m = mask;
    while (m) {
        int bpos = __builtin_ctzll(m);
        m &= m - 1;
        int i = bpos >> 2, j = bpos & 3;
        int e = i * 256 + lane * 4 + j;
        if (pos < CAP) adjrow[pos] = e;
        ++pos;
        int slot = atomicAdd(&cntENp[(t * E_ + e) * 16], 1);
        if (slot < CAP) adjEN[((size_t)(t * E_ + e)) * CAP + slot] = n_id;
    }
    if (lane == 63) {
        cntNE[row] = incl < CAP ? incl : CAP;
        dVis[row] = incl > 0 ? rsqrtf((float)incl) : 0.0f;
    }
}

// ---------------------------------------------------------------------------
// xw: y[t,n,:] = dVis * (xsrc @ W[l,t]^T + b[l,t]); 64x64 tiles, K-chunk 32
// in LDS, 4x4 register tile. 256 tiles grid-strided.
__device__ __forceinline__ void xw_phase(int l, const float* __restrict__ xsrc,
        const float* __restrict__ W, const float* __restrict__ b,
        const float* __restrict__ dVis, float* __restrict__ y,
        float* s_xs, float* s_ws) {
    for (int slot = blockIdx.x; slot < 256; slot += GRID) {
        int t = slot >> 7;
        int nb = (slot >> 1) & 63, ob = slot & 1;
        int n0 = nb * 64, o0 = ob * 64;
        int tid = threadIdx.x;
        int tx = tid & 15, ty = tid >> 4;
        const float* Wg = W + ((size_t)(l * T_ + t) * D_ + o0) * D_;
        const float* xg = xsrc + (size_t)n0 * D_;
        float acc[4][4] = {};
        for (int kc = 0; kc < 4; ++kc) {
            __syncthreads();
            for (int i = tid; i < 512; i += NTHR) {
                int r = i >> 3, k4 = i & 7;
                *(float4*)(s_xs + r * 36 + k4 * 4) =
                    *(const float4*)(xg + (size_t)r * D_ + kc * 32 + k4 * 4);
                int k4s = k4 ^ ((r >> 2) & 7);
                *(float4*)(s_ws + r * 32 + k4s * 4) =
                    *(const float4*)(Wg + (size_t)r * D_ + kc * 32 + k4 * 4);
            }
            __syncthreads();
            #pragma unroll
            for (int k4 = 0; k4 < 8; ++k4) {
                float4 xv[4], wv[4];
                #pragma unroll
                for (int rr = 0; rr < 4; ++rr)
                    xv[rr] = *(const float4*)(s_xs + (ty * 4 + rr) * 36 + k4 * 4);
                int k4s = k4 ^ (tx & 7);
                #pragma unroll
                for (int cc = 0; cc < 4; ++cc)
                    wv[cc] = *(const float4*)(s_ws + (tx * 4 + cc) * 32 + k4s * 4);
                #pragma unroll
                for (int rr = 0; rr < 4; ++rr)
                    #pragma unroll
                    for (int cc = 0; cc < 4; ++cc)
                        acc[rr][cc] += xv[rr].x * wv[cc].x + xv[rr].y * wv[cc].y
                                     + xv[rr].z * wv[cc].z + xv[rr].w * wv[cc].w;
            }
        }
        const float* bg = b + (size_t)(l * T_ + t) * D_;
        float4 bv = *(const float4*)(bg + o0 + tx * 4);
        #pragma unroll
        for (int rr = 0; rr < 4; ++rr) {
            int n = n0 + ty * 4 + rr;
            float s = dVis[t * N_ + n];
            float4 ov;
            ov.x = s * (acc[rr][0] + bv.x);
            ov.y = s * (acc[rr][1] + bv.y);
            ov.z = s * (acc[rr][2] + bv.z);
            ov.w = s * (acc[rr][3] + bv.w);
            *(float4*)(y + ((size_t)(t * N_ + n)) * D_ + o0 + tx * 4) = ov;
        }
        __syncthreads();
    }
}

// ---------------------------------------------------------------------------
__device__ __forceinline__ void ye_row(int vr, int d, const float* __restrict__ y,
        const float* __restrict__ dEinv, const int* __restrict__ cntEN,
        const int* __restrict__ adjEN, float* __restrict__ yebuf) {
    int t = vr >> 12;
    int c = cntEN[vr];
    const int* row = adjEN + (size_t)vr * CAP;
    const float* src = y + (size_t)t * N_ * D_;
    float s = 0.0f;
    for (int j0 = 0; j0 < c; j0 += 4) {
        int4 ids = *reinterpret_cast<const int4*>(row + j0);
        s += src[(size_t)ids.x * D_ + d];
        if (j0 + 1 < c) s += src[(size_t)ids.y * D_ + d];
        if (j0 + 2 < c) s += src[(size_t)ids.z * D_ + d];
        if (j0 + 3 < c) s += src[(size_t)ids.w * D_ + d];
    }
    yebuf[(size_t)vr * D_ + d] = dEinv[vr] * s;
}

__device__ __forceinline__ void e_row(int n, int d, const float* __restrict__ yebuf,
        const float* __restrict__ dVis, const int* __restrict__ cntNE,
        const int* __restrict__ adjNE, float* __restrict__ ebuf,
        const float* __restrict__ x0, float* __restrict__ xsum0,
        float* __restrict__ outnode, int last) {
    float xnew = 0.0f;
    #pragma unroll
    for (int t = 0; t < T_; ++t) {
        int r = t * N_ + n;
        int c = cntNE[r];
        const int* row = adjNE + (size_t)r * CAP;
        const float* src = yebuf + (size_t)t * E_ * D_;
        float s = 0.0f;
        for (int j0 = 0; j0 < c; j0 += 4) {
            int4 ids = *reinterpret_cast<const int4*>(row + j0);
            s += src[(size_t)ids.x * D_ + d];
            if (j0 + 1 < c) s += src[(size_t)ids.y * D_ + d];
            if (j0 + 2 < c) s += src[(size_t)ids.z * D_ + d];
            if (j0 + 3 < c) s += src[(size_t)ids.w * D_ + d];
        }
        float ev = dVis[r] * s;
        ev = ev >= 0.0f ? ev : 0.01f * ev;
        ebuf[(size_t)r * D_ + d] = ev;
        xnew += ev;
    }
    size_t i = (size_t)n * D_ + d;
    if (!last) xsum0[i] = xnew;
    else outnode[i] = (x0[i] + xsum0[i] + xnew) * (1.0f / 3.0f);
}

__device__ __forceinline__ void o_row(int e, int d, const float* __restrict__ ebuf,
        const float* __restrict__ dEinv, const int* __restrict__ cntEN,
        const int* __restrict__ adjEN, float* __restrict__ revacc,
        float* __restrict__ outrev, int last) {
    float acc = 0.0f;
    #pragma unroll
    for (int t = 0; t < T_; ++t) {
        int r = t * E_ + e;
        int c = cntEN[r];
        const int* row = adjEN + (size_t)r * CAP;
        const float* src = ebuf + (size_t)t * N_ * D_;
        float s = 0.0f;
        for (int j0 = 0; j0 < c; j0 += 4) {
            int4 ids = *reinterpret_cast<const int4*>(row + j0);
            s += src[(size_t)ids.x * D_ + d];
            if (j0 + 1 < c) s += src[(size_t)ids.y * D_ + d];
            if (j0 + 2 < c) s += src[(size_t)ids.z * D_ + d];
            if (j0 + 3 < c) s += src[(size_t)ids.w * D_ + d];
        }
        acc += dEinv[r] * s;
    }
    size_t i = (size_t)e * D_ + d;
    if (!last) revacc[i] = acc;
    else outrev[i] = (revacc[i] + acc) * 0.5f;
}

// ---------------------------------------------------------------------------
// phase < 0: cooperative, all phases with grid.sync between.
// phase >= 0: run just that phase (fallback path, one launch per phase).
__global__ void __launch_bounds__(NTHR, 2) mega(int phase,
        const float* __restrict__ x, const float* __restrict__ H,
        const float* __restrict__ W, const float* __restrict__ b,
        float* __restrict__ outnode, float* __restrict__ outrev,
        float* __restrict__ dVis, float* __restrict__ dEinv,
        int* __restrict__ cntNE, int* __restrict__ cntEN, int* __restrict__ cntENp,
        int* __restrict__ adjNE, int* __restrict__ adjEN,
        float* __restrict__ y, float* __restrict__ yebuf, float* __restrict__ ebuf,
        float* __restrict__ xsum0, float* __restrict__ revacc) {
    __shared__ float s_xs[64 * 36];
    __shared__ float s_ws[64 * 32];
    int tid = threadIdx.x;
    int gtid = blockIdx.x * NTHR + tid;
    int half = tid >> 7, d = tid & 127;
    int lane = tid & 63, wid = tid >> 6;
    bool all = (phase < 0);
#define GSYNC() do { if (all) cg::this_grid().sync(); } while (0)

    // P0: zero padded edge counters
    if (all || phase == 0) {
        if (gtid < T_ * E_) cntENp[gtid * 16] = 0;
    }
    GSYNC();
    // P1: build adjacency, one wave per row
    if (all || phase == 1) {
        for (int row = blockIdx.x * 4 + wid; row < T_ * N_; row += GRID * 4)
            build_row_wave(row, lane, H, dVis, cntNE, adjNE, cntENp, adjEN);
    }
    GSYNC();
    // P2: finalize edge side (clamp, dEinv, canonical sort)
    if (all || phase == 2) {
        if (gtid < T_ * E_) {
            int c = cntENp[gtid * 16];
            if (c > CAP) c = CAP;
            cntEN[gtid] = c;
            dEinv[gtid] = c > 0 ? 1.0f / (float)c : 0.0f;
            int* arow = adjEN + (size_t)gtid * CAP;
            for (int a = 1; a < c; ++a) {
                int key = arow[a];
                int bb = a - 1;
                while (bb >= 0 && arow[bb] > key) { arow[bb + 1] = arow[bb]; --bb; }
                arow[bb + 1] = key;
            }
        }
    }
    GSYNC();
    // P3: xw layer 0
    if (all || phase == 3) xw_phase(0, x, W, b, dVis, y, s_xs, s_ws);
    GSYNC();
    // P4: ye layer 0
    if (all || phase == 4) {
        for (int vr = blockIdx.x * 2 + half; vr < T_ * E_; vr += GRID * 2)
            ye_row(vr, d, y, dEinv, cntEN, adjEN, yebuf);
    }
    GSYNC();
    // P5: e layer 0 (writes ebuf + xsum0)
    if (all || phase == 5) {
        for (int n = blockIdx.x * 2 + half; n < N_; n += GRID * 2)
            e_row(n, d, yebuf, dVis, cntNE, adjNE, ebuf, x, xsum0, outnode, 0);
    }
    GSYNC();
    // P6: xw layer 1 (input = xsum0)
    if (all || phase == 6) xw_phase(1, xsum0, W, b, dVis, y, s_xs, s_ws);
    GSYNC();
    // P7: ye layer 1 || o layer 0 (independent work items)
    if (all || phase == 7) {
        for (int vr = blockIdx.x * 2 + half; vr < T_ * E_ + E_; vr += GRID * 2) {
            if (vr < T_ * E_) ye_row(vr, d, y, dEinv, cntEN, adjEN, yebuf);
            else o_row(vr - T_ * E_, d, ebuf, dEinv, cntEN, adjEN, revacc, outrev, 0);
        }
    }
    GSYNC();
    // P8: e layer 1 (writes ebuf + outnode)
    if (all || phase == 8) {
        for (int n = blockIdx.x * 2 + half; n < N_; n += GRID * 2)
            e_row(n, d, yebuf, dVis, cntNE, adjNE, ebuf, x, xsum0, outnode, 1);
    }
    GSYNC();
    // P9: o layer 1 (writes outrev)
    if (all || phase == 9) {
        for (int e = blockIdx.x * 2 + half; e < E_; e += GRID * 2)
            o_row(e, d, ebuf, dEinv, cntEN, adjEN, revacc, outrev, 1);
    }
#undef GSYNC
}

// ---------------------------------------------------------------------------
extern "C" void kernel_launch(void* const* d_in, const int* in_sizes, int n_in,
                              void* d_out, int out_size, void* d_ws, size_t ws_size,
                              hipStream_t stream) {
    const float* x = (const float*)d_in[0];
    const float* H = (const float*)d_in[1];
    const float* W = (const float*)d_in[2];
    const float* b = (const float*)d_in[3];
    float* outnode = (float*)d_out;
    float* outrev  = (float*)d_out + (size_t)N_ * D_;

    char* p = (char*)d_ws;
    auto alloc = [&](size_t bytes) {
        char* r = p;
        p += (bytes + 255) & ~(size_t)255;
        return r;
    };
    float* dVis   = (float*)alloc((size_t)T_ * N_ * 4);
    float* dEinv  = (float*)alloc((size_t)T_ * E_ * 4);
    int*   cntNE  = (int*)  alloc((size_t)T_ * N_ * 4);
    int*   cntEN  = (int*)  alloc((size_t)T_ * E_ * 4);
    int*   cntENp = (int*)  alloc((size_t)T_ * E_ * 16 * 4);   // 1 counter / 64B line
    int*   adjNE  = (int*)  alloc((size_t)T_ * N_ * CAP * 4);
    int*   adjEN  = (int*)  alloc((size_t)T_ * E_ * CAP * 4);
    float* y      = (float*)alloc((size_t)T_ * N_ * D_ * 4);
    float* yebuf  = (float*)alloc((size_t)T_ * E_ * D_ * 4);
    float* ebuf   = (float*)alloc((size_t)T_ * N_ * D_ * 4);
    float* xsum0  = (float*)alloc((size_t)N_ * D_ * 4);
    float* revacc = (float*)alloc((size_t)E_ * D_ * 4);

    int phase = -1;
    void* args[] = {
        (void*)&phase,
        (void*)&x, (void*)&H, (void*)&W, (void*)&b,
        (void*)&outnode, (void*)&outrev,
        (void*)&dVis, (void*)&dEinv,
        (void*)&cntNE, (void*)&cntEN, (void*)&cntENp,
        (void*)&adjNE, (void*)&adjEN,
        (void*)&y, (void*)&yebuf, (void*)&ebuf,
        (void*)&xsum0, (void*)&revacc,
    };
    hipError_t err = hipLaunchCooperativeKernel((const void*)mega, dim3(GRID),
                                                dim3(NTHR), args, 0, stream);
    if (err != hipSuccess) {
        (void)hipGetLastError();   // clear sticky error, take the fallback path
        for (int ph = 0; ph <= 9; ++ph) {
            mega<<<GRID, NTHR, 0, stream>>>(ph, x, H, W, b, outnode, outrev,
                dVis, dEinv, cntNE, cntEN, cntENp, adjNE, adjEN,
                y, yebuf, ebuf, xsum0, revacc);
        }
    }
}

// Round 5
// 119.997 us; speedup vs baseline: 6.2936x; 6.2936x over previous
//
#include <hip/hip_runtime.h>

#define T_ 2
#define N_ 4096
#define E_ 4096
#define D_ 128
#define CAP 64     // max stored nnz per row/col; Binomial(4096,0.002) mean 8.2 -> P(>64) ~ 0
#define D4 (D_ / 4)   // 32 float4 per feature row

// ---------------------------------------------------------------------------
// build: one 256-thr block per H row. 4 lane-coalesced float4 loads/thread ->
// 16-bit nnz mask -> block prefix scan -> ordered adjNE append. Edge side via
// atomic append on padded counters (one per 64B line); order nondeterministic
// but fp-sum wobble ~1e-6 << 3.4e-2 threshold.
__global__ __launch_bounds__(256) void k_build(const float* __restrict__ H,
                        float* __restrict__ dVis,
                        int* __restrict__ cntNE, int* __restrict__ adjNE,
                        int* __restrict__ cntENp, int* __restrict__ adjEN) {
    int bid = blockIdx.x;          // t*N + n
    int t = bid >> 12;             // N_ = 4096
    int tid = threadIdx.x;
    int lane = tid & 63, wid = tid >> 6;
    const float4* row4 = (const float4*)(H + (size_t)bid * E_);
    float4 v[4];
    #pragma unroll
    for (int i = 0; i < 4; ++i) v[i] = row4[i * 256 + tid];   // 1KB/instr coalesced
    unsigned mask = 0;
    #pragma unroll
    for (int i = 0; i < 4; ++i) {
        if (v[i].x != 0.0f) mask |= 1u << (i * 4 + 0);
        if (v[i].y != 0.0f) mask |= 1u << (i * 4 + 1);
        if (v[i].z != 0.0f) mask |= 1u << (i * 4 + 2);
        if (v[i].w != 0.0f) mask |= 1u << (i * 4 + 3);
    }
    int cnt = __popc(mask);
    int incl = cnt;                       // wave-inclusive scan
    #pragma unroll
    for (int off = 1; off < 64; off <<= 1) {
        int u = __shfl_up(incl, off);
        if (lane >= off) incl += u;
    }
    __shared__ int wsum[4];
    if (lane == 63) wsum[wid] = incl;
    __syncthreads();
    int wbase = 0;
    #pragma unroll
    for (int w = 0; w < 4; ++w) if (w < wid) wbase += wsum[w];
    int pos = wbase + incl - cnt;         // exclusive prefix across block
    int* adjrow = adjNE + (size_t)bid * CAP;
    int n_id = bid & (N_ - 1);
    unsigned m = mask;
    while (m) {
        int bpos = __ffs((int)m) - 1;
        m &= m - 1;
        int i = bpos >> 2, j = bpos & 3;
        int e = (i * 256 + tid) * 4 + j;
        if (pos < CAP) adjrow[pos] = e;
        ++pos;
        int slot = atomicAdd(&cntENp[(t * E_ + e) * 16], 1);
        if (slot < CAP) adjEN[((size_t)(t * E_ + e)) * CAP + slot] = n_id;
    }
    if (tid == 255) {
        int total = wbase + incl;
        cntNE[bid] = total < CAP ? total : CAP;
        dVis[bid] = total > 0 ? rsqrtf((float)total) : 0.0f;
    }
}

// ---------------------------------------------------------------------------
// xw: y[t,n,:] = dVis * (xsrc @ W[l,t]^T + b[l,t]); one 64x64 tile per block,
// K-chunk 32 through LDS (17.4KB), 4x4 register tile. grid = 256.
__global__ __launch_bounds__(256) void k_xw(const float* __restrict__ xsrc,
        const float* __restrict__ W, const float* __restrict__ b,
        const float* __restrict__ dVis, float* __restrict__ y, int l) {
    __shared__ float s_xs[64 * 36];
    __shared__ float s_ws[64 * 32];
    int slot = blockIdx.x;
    int t = slot >> 7;
    int nb = (slot >> 1) & 63, ob = slot & 1;
    int n0 = nb * 64, o0 = ob * 64;
    int tid = threadIdx.x;
    int tx = tid & 15, ty = tid >> 4;
    const float* Wg = W + ((size_t)(l * T_ + t) * D_ + o0) * D_;
    const float* xg = xsrc + (size_t)n0 * D_;
    float acc[4][4] = {};
    for (int kc = 0; kc < 4; ++kc) {
        __syncthreads();
        for (int i = tid; i < 512; i += 256) {
            int r = i >> 3, k4 = i & 7;
            *(float4*)(s_xs + r * 36 + k4 * 4) =
                *(const float4*)(xg + (size_t)r * D_ + kc * 32 + k4 * 4);
            int k4s = k4 ^ ((r >> 2) & 7);
            *(float4*)(s_ws + r * 32 + k4s * 4) =
                *(const float4*)(Wg + (size_t)r * D_ + kc * 32 + k4 * 4);
        }
        __syncthreads();
        #pragma unroll
        for (int k4 = 0; k4 < 8; ++k4) {
            float4 xv[4], wv[4];
            #pragma unroll
            for (int rr = 0; rr < 4; ++rr)
                xv[rr] = *(const float4*)(s_xs + (ty * 4 + rr) * 36 + k4 * 4);
            int k4s = k4 ^ (tx & 7);
            #pragma unroll
            for (int cc = 0; cc < 4; ++cc)
                wv[cc] = *(const float4*)(s_ws + (tx * 4 + cc) * 32 + k4s * 4);
            #pragma unroll
            for (int rr = 0; rr < 4; ++rr)
                #pragma unroll
                for (int cc = 0; cc < 4; ++cc)
                    acc[rr][cc] += xv[rr].x * wv[cc].x + xv[rr].y * wv[cc].y
                                 + xv[rr].z * wv[cc].z + xv[rr].w * wv[cc].w;
        }
    }
    const float* bg = b + (size_t)(l * T_ + t) * D_;
    float4 bv = *(const float4*)(bg + o0 + tx * 4);
    #pragma unroll
    for (int rr = 0; rr < 4; ++rr) {
        int n = n0 + ty * 4 + rr;
        float s = dVis[t * N_ + n];
        float4 ov;
        ov.x = s * (acc[rr][0] + bv.x);
        ov.y = s * (acc[rr][1] + bv.y);
        ov.z = s * (acc[rr][2] + bv.z);
        ov.w = s * (acc[rr][3] + bv.w);
        *(float4*)(y + ((size_t)(t * N_ + n)) * D_ + o0 + tx * 4) = ov;
    }
}

// ---------------------------------------------------------------------------
// float4 gather helpers: 32 threads (q=0..31) cover one feature row.
__device__ __forceinline__ float4 gather_sum4(const float4* __restrict__ src,
        const int* __restrict__ row, int c, int q) {
    float4 s = {0.f, 0.f, 0.f, 0.f};
    for (int j0 = 0; j0 < c; j0 += 4) {
        int4 ids = *reinterpret_cast<const int4*>(row + j0);
        float4 a = src[(size_t)ids.x * D4 + q];
        s.x += a.x; s.y += a.y; s.z += a.z; s.w += a.w;
        if (j0 + 1 < c) { a = src[(size_t)ids.y * D4 + q]; s.x += a.x; s.y += a.y; s.z += a.z; s.w += a.w; }
        if (j0 + 2 < c) { a = src[(size_t)ids.z * D4 + q]; s.x += a.x; s.y += a.y; s.z += a.z; s.w += a.w; }
        if (j0 + 3 < c) { a = src[(size_t)ids.w * D4 + q]; s.x += a.x; s.y += a.y; s.z += a.z; s.w += a.w; }
    }
    return s;
}

__device__ __forceinline__ void ye_one(int vr, int q, const float4* __restrict__ y4,
        const int* __restrict__ cntENp, const int* __restrict__ adjEN,
        float4* __restrict__ ye4) {
    int t = vr >> 12;
    int c = cntENp[vr * 16];
    if (c > CAP) c = CAP;
    float dE = c > 0 ? 1.0f / (float)c : 0.0f;
    float4 s = gather_sum4(y4 + (size_t)t * N_ * D4, adjEN + (size_t)vr * CAP, c, q);
    float4 o = {dE * s.x, dE * s.y, dE * s.z, dE * s.w};
    ye4[(size_t)vr * D4 + q] = o;
}

__device__ __forceinline__ void o_one(int e, int q, const float4* __restrict__ e4,
        const int* __restrict__ cntENp, const int* __restrict__ adjEN,
        float4* __restrict__ revacc4, float4* __restrict__ outrev4, int last) {
    float4 acc = {0.f, 0.f, 0.f, 0.f};
    #pragma unroll
    for (int t = 0; t < T_; ++t) {
        int r = t * E_ + e;
        int c = cntENp[r * 16];
        if (c > CAP) c = CAP;
        float dE = c > 0 ? 1.0f / (float)c : 0.0f;
        float4 s = gather_sum4(e4 + (size_t)t * N_ * D4, adjEN + (size_t)r * CAP, c, q);
        acc.x += dE * s.x; acc.y += dE * s.y; acc.z += dE * s.z; acc.w += dE * s.w;
    }
    size_t i = (size_t)e * D4 + q;
    if (!last) revacc4[i] = acc;
    else {
        float4 ra = revacc4[i];
        float4 o = {(ra.x + acc.x) * 0.5f, (ra.y + acc.y) * 0.5f,
                    (ra.z + acc.z) * 0.5f, (ra.w + acc.w) * 0.5f};
        outrev4[i] = o;
    }
}

// ---------------------------------------------------------------------------
// ye kernel (layer given); 8 rows per 256-thr block.
__global__ __launch_bounds__(256) void k_ye(const float* __restrict__ y,
        const int* __restrict__ cntENp, const int* __restrict__ adjEN,
        float* __restrict__ yebuf) {
    int vr = blockIdx.x * 8 + (threadIdx.x >> 5);
    int q = threadIdx.x & 31;
    ye_one(vr, q, (const float4*)y, cntENp, adjEN, (float4*)yebuf);
}

// ye layer 1 fused with o layer 0: slots [0,8192) = ye rows, [8192,12288) = o rows.
__global__ __launch_bounds__(256) void k_ye_o(const float* __restrict__ y,
        const float* __restrict__ ebuf,
        const int* __restrict__ cntENp, const int* __restrict__ adjEN,
        float* __restrict__ yebuf, float* __restrict__ revacc) {
    int slot = blockIdx.x * 8 + (threadIdx.x >> 5);
    int q = threadIdx.x & 31;
    if (slot < T_ * E_)
        ye_one(slot, q, (const float4*)y, cntENp, adjEN, (float4*)yebuf);
    else
        o_one(slot - T_ * E_, q, (const float4*)ebuf, cntENp, adjEN,
              (float4*)revacc, nullptr, 0);
}

// e kernel: e[t,n,:]=leaky(dVis*sum ye); writes ebuf; layer0 -> xsum0,
// layer1 -> outnode = (x + xsum0 + xnew)/3. 8 nodes per block.
__global__ __launch_bounds__(256) void k_e(const float* __restrict__ yebuf,
        const float* __restrict__ dVis, const int* __restrict__ cntNE,
        const int* __restrict__ adjNE, float* __restrict__ ebuf,
        const float* __restrict__ x0, float* __restrict__ xsum0,
        float* __restrict__ outnode, int last) {
    int n = blockIdx.x * 8 + (threadIdx.x >> 5);
    int q = threadIdx.x & 31;
    const float4* ye4 = (const float4*)yebuf;
    float4* e4 = (float4*)ebuf;
    float4 xnew = {0.f, 0.f, 0.f, 0.f};
    #pragma unroll
    for (int t = 0; t < T_; ++t) {
        int r = t * N_ + n;
        int c = cntNE[r];
        float4 s = gather_sum4(ye4 + (size_t)t * E_ * D4, adjNE + (size_t)r * CAP, c, q);
        float dv = dVis[r];
        float4 ev;
        ev.x = dv * s.x; ev.x = ev.x >= 0.f ? ev.x : 0.01f * ev.x;
        ev.y = dv * s.y; ev.y = ev.y >= 0.f ? ev.y : 0.01f * ev.y;
        ev.z = dv * s.z; ev.z = ev.z >= 0.f ? ev.z : 0.01f * ev.z;
        ev.w = dv * s.w; ev.w = ev.w >= 0.f ? ev.w : 0.01f * ev.w;
        e4[(size_t)r * D4 + q] = ev;
        xnew.x += ev.x; xnew.y += ev.y; xnew.z += ev.z; xnew.w += ev.w;
    }
    size_t i = (size_t)n * D4 + q;
    if (!last) ((float4*)xsum0)[i] = xnew;
    else {
        float4 xv = ((const float4*)x0)[i];
        float4 xs = ((const float4*)xsum0)[i];
        float4 o = {(xv.x + xs.x + xnew.x) * (1.0f / 3.0f),
                    (xv.y + xs.y + xnew.y) * (1.0f / 3.0f),
                    (xv.z + xs.z + xnew.z) * (1.0f / 3.0f),
                    (xv.w + xs.w + xnew.w) * (1.0f / 3.0f)};
        ((float4*)outnode)[i] = o;
    }
}

// o kernel (last layer): outrev = (revacc + o1)/2. 8 edges per block.
__global__ __launch_bounds__(256) void k_o(const float* __restrict__ ebuf,
        const int* __restrict__ cntENp, const int* __restrict__ adjEN,
        float* __restrict__ revacc, float* __restrict__ outrev) {
    int e = blockIdx.x * 8 + (threadIdx.x >> 5);
    int q = threadIdx.x & 31;
    o_one(e, q, (const float4*)ebuf, cntENp, adjEN, (float4*)revacc,
          (float4*)outrev, 1);
}

// ---------------------------------------------------------------------------
extern "C" void kernel_launch(void* const* d_in, const int* in_sizes, int n_in,
                              void* d_out, int out_size, void* d_ws, size_t ws_size,
                              hipStream_t stream) {
    const float* x = (const float*)d_in[0];
    const float* H = (const float*)d_in[1];
    const float* W = (const float*)d_in[2];
    const float* b = (const float*)d_in[3];
    float* outnode = (float*)d_out;
    float* outrev  = (float*)d_out + (size_t)N_ * D_;

    char* p = (char*)d_ws;
    auto alloc = [&](size_t bytes) {
        char* r = p;
        p += (bytes + 255) & ~(size_t)255;
        return r;
    };
    float* dVis   = (float*)alloc((size_t)T_ * N_ * 4);
    int*   cntNE  = (int*)  alloc((size_t)T_ * N_ * 4);
    int*   cntENp = (int*)  alloc((size_t)T_ * E_ * 16 * 4);   // 1 counter / 64B line
    int*   adjNE  = (int*)  alloc((size_t)T_ * N_ * CAP * 4);
    int*   adjEN  = (int*)  alloc((size_t)T_ * E_ * CAP * 4);
    float* y      = (float*)alloc((size_t)T_ * N_ * D_ * 4);
    float* yebuf  = (float*)alloc((size_t)T_ * E_ * D_ * 4);
    float* ebuf   = (float*)alloc((size_t)T_ * N_ * D_ * 4);
    float* xsum0  = (float*)alloc((size_t)N_ * D_ * 4);
    float* revacc = (float*)alloc((size_t)E_ * D_ * 4);

    hipMemsetAsync(cntENp, 0, (size_t)T_ * E_ * 16 * 4, stream);
    k_build<<<T_ * N_, 256, 0, stream>>>(H, dVis, cntNE, adjNE, cntENp, adjEN);

    // layer 0
    k_xw<<<256, 256, 0, stream>>>(x, W, b, dVis, y, 0);
    k_ye<<<T_ * E_ / 8, 256, 0, stream>>>(y, cntENp, adjEN, yebuf);
    k_e<<<N_ / 8, 256, 0, stream>>>(yebuf, dVis, cntNE, adjNE, ebuf, x, xsum0,
                                    outnode, 0);
    // layer 1 (o layer 0 fused into ye layer 1)
    k_xw<<<256, 256, 0, stream>>>(xsum0, W, b, dVis, y, 1);
    k_ye_o<<<(T_ * E_ + E_) / 8, 256, 0, stream>>>(y, ebuf, cntENp, adjEN,
                                                   yebuf, revacc);
    k_e<<<N_ / 8, 256, 0, stream>>>(yebuf, dVis, cntNE, adjNE, ebuf, x, xsum0,
                                    outnode, 1);
    k_o<<<E_ / 8, 256, 0, stream>>>(ebuf, cntENp, adjEN, revacc, outrev);
}